// Round 9
// baseline (357.507 us; speedup 1.0000x reference)
//
#include <hip/hip_runtime.h>

#define NN 4096      // reviews
#define LL 128       // tokens
#define DD 200       // word dim
#define AA 32        // aspects
#define NEG 5
#define BB 1024      // users/items

// workspace layout (float offsets)
#define WS_RS    0
#define WS_ACC   (NN*DD)   // [0]=J_sum [1]=U_mean [2]=RL_sum [8]=done(int)

// ---------------- DPP reductions (VALU, no DS pipe) -------------------------
template<int C, int RM>
__device__ __forceinline__ float dpp_add(float v){
  int t = __builtin_amdgcn_update_dpp(0, __float_as_int(v), C, RM, 0xf, false);
  return v + __int_as_float(t);
}
template<int C, int RM>
__device__ __forceinline__ float dpp_fmax(float v){
  int t = __builtin_amdgcn_update_dpp(__float_as_int(-3.0e38f), __float_as_int(v),
                                      C, RM, 0xf, false);
  return fmaxf(v, __int_as_float(t));
}
// full 64-lane sum; valid in lane 63
__device__ __forceinline__ float sum64(float v){
  v = dpp_add<0xB1, 0xF>(v);
  v = dpp_add<0x4E, 0xF>(v);
  v = dpp_add<0x124,0xF>(v);
  v = dpp_add<0x128,0xF>(v);
  v = dpp_add<0x142,0xA>(v);
  v = dpp_add<0x143,0xC>(v);
  return v;
}
__device__ __forceinline__ float max64(float v){
  v = dpp_fmax<0xB1, 0xF>(v);
  v = dpp_fmax<0x4E, 0xF>(v);
  v = dpp_fmax<0x124,0xF>(v);
  v = dpp_fmax<0x128,0xF>(v);
  v = dpp_fmax<0x142,0xA>(v);
  v = dpp_fmax<0x143,0xC>(v);
  return v;
}
// 8-lane (octet) sum: valid at lanes j%8==0
__device__ __forceinline__ float sum8(float v){
  v = dpp_add<0xB1, 0xF>(v);
  v = dpp_add<0x4E, 0xF>(v);
  v = dpp_add<0x124,0xF>(v);
  return v;
}
__device__ __forceinline__ float rdlane(float v, int l){
  return __int_as_float(__builtin_amdgcn_readlane(__float_as_int(v), l));
}
__device__ __forceinline__ float dot4(float4 a, float4 b){
  return a.x*b.x + a.y*b.y + a.z*b.z + a.w*b.w;
}
__device__ __forceinline__ float4 smx4(float4 r, float M, float invS){
  float4 o;
  o.x = __expf(r.x - M) * invS; o.y = __expf(r.y - M) * invS;
  o.z = __expf(r.z - M) * invS; o.w = __expf(r.w - M) * invS;
  return o;
}

// z-pass helpers: octet (8 lanes) per d2, lane q covers l2 = 32i+4q..+3
__device__ __forceinline__ void z_load(float4* buf, const float* __restrict__ we,
                                       const int* hrowl, int d2, int q){
  unsigned f0 = (unsigned)d2 * 128u + 4u * (unsigned)q;
#pragma unroll
  for (int i = 0; i < 4; ++i){
    unsigned f = f0 + 32u * i;
    unsigned r = f / 200u;
    buf[i] = *(const float4*)(we + (size_t)hrowl[r] * DD + (f - r * 200u));
  }
}
__device__ __forceinline__ float z_red(const float4* buf, const float4* ax){
  return dot4(buf[0],ax[0]) + dot4(buf[1],ax[1]) + dot4(buf[2],ax[2]) + dot4(buf[3],ax[3]);
}

// ---- main per-review kernel ------------------------------------------------
// LDS (floats): y_l[0,200) dxax[208,336) zsm[336,536) r_l[536,736)
//               lsps[736,768) sc[768,776) hrowl(int)[776,904) ypart[904,1704)
__global__ __launch_bounds__(256, 7)
void k_main(const int* __restrict__ hist, const float* __restrict__ rev_pos,
            const float* __restrict__ rev_neg, const float* __restrict__ word_emb,
            const float* __restrict__ M_w, const float* __restrict__ W_w,
            const float* __restrict__ W_b, const float* __restrict__ T_w,
            float* __restrict__ rs_out, float* __restrict__ acc)
{
  __shared__ __align__(16) float smem[1704];
  float* y_l  = smem;
  float* dxax = smem + 208;
  float* zsm  = smem + 336;
  float* r_l  = smem + 536;   // holds rp first, r_s later
  float* lsps = smem + 736;
  float* sc   = smem + 768;
  int*   hrowl= (int*)(smem + 776);
  float* ypart= smem + 904;

  const int n = blockIdx.x;
  const int t = threadIdx.x;
  const int w = t >> 6, j = t & 63;
  const int wu = __builtin_amdgcn_readfirstlane(w);

  if (t < DD) r_l[t] = rev_pos[(size_t)n * DD + t];
  if (t < LL) hrowl[t] = hist[(size_t)n * LL + t];
  __syncthreads();

  // ---- y = rp @ M, split-K across waves: wave w covers d in [50w,50w+50) --
  if (j < 50){
    float ax = 0.f, ay = 0.f, az = 0.f, aw = 0.f;
    const float* Mb = M_w + (50 * wu) * DD + 4 * j;
    const float* rb = r_l + 50 * wu;
#pragma unroll 10
    for (int dk = 0; dk < 50; ++dk){
      float rv = rb[dk];
      float4 m4 = *(const float4*)(Mb + dk * DD);
      ax = fmaf(rv, m4.x, ax); ay = fmaf(rv, m4.y, ay);
      az = fmaf(rv, m4.z, az); aw = fmaf(rv, m4.w, aw);
    }
    float4 o; o.x = ax; o.y = ay; o.z = az; o.w = aw;
    *(float4*)(ypart + wu * 200 + 4 * j) = o;
  }
  __syncthreads();
  if (t < DD) y_l[t] = ypart[t] + ypart[200 + t] + ypart[400 + t] + ypart[600 + t];
  __syncthreads();

  // ---- dx[l]: wave w owns rows [32w,32w+32); SGPR row ids; 8-deep batches;
  //      reduce/load rotation; z-prologue loads issued inside the same region.
  const int q = j & 7, oct = j >> 3;
  int d2c[7];
#pragma unroll
  for (int k = 0; k < 7; ++k){
    int off = 8 * k + oct;
    d2c[k] = 50 * wu + (off < 50 ? off : 49);   // clamp; store guarded later
  }
  float4 za[4], zb[4];
  {
    float4 y4 = make_float4(0.f, 0.f, 0.f, 0.f);
    int col = 0;
    if (j < 50){ y4 = *(const float4*)(y_l + 4 * j); col = 4 * j; }
    const int* hrow_g = hist + (size_t)n * LL + 32 * wu;   // wave-uniform base
    int rA[8], rB[8];
    float4 gA[8], gB[8];
    // load batch0, batch1
#pragma unroll
    for (int i = 0; i < 8; ++i) rA[i] = hrow_g[i];         // s_load
#pragma unroll
    for (int i = 0; i < 8; ++i)
      gA[i] = *(const float4*)(word_emb + (size_t)rA[i] * DD + col);
#pragma unroll
    for (int i = 0; i < 8; ++i) rB[i] = hrow_g[8 + i];
#pragma unroll
    for (int i = 0; i < 8; ++i)
      gB[i] = *(const float4*)(word_emb + (size_t)rB[i] * DD + col);
    // reduce batch0
#pragma unroll
    for (int i = 0; i < 8; ++i){
      float v = sum64(dot4(gA[i], y4));
      if (j == 63) dxax[32 * wu + i] = v;
    }
    // load batch2
#pragma unroll
    for (int i = 0; i < 8; ++i) rA[i] = hrow_g[16 + i];
#pragma unroll
    for (int i = 0; i < 8; ++i)
      gA[i] = *(const float4*)(word_emb + (size_t)rA[i] * DD + col);
    // reduce batch1
#pragma unroll
    for (int i = 0; i < 8; ++i){
      float v = sum64(dot4(gB[i], y4));
      if (j == 63) dxax[32 * wu + 8 + i] = v;
    }
    // load batch3
#pragma unroll
    for (int i = 0; i < 8; ++i) rB[i] = hrow_g[24 + i];
#pragma unroll
    for (int i = 0; i < 8; ++i)
      gB[i] = *(const float4*)(word_emb + (size_t)rB[i] * DD + col);
    // z prologue: issue iters 0,1 now — latency hides under batch2/3 reduces
    z_load(za, word_emb, hrowl, d2c[0], q);
    z_load(zb, word_emb, hrowl, d2c[1], q);
    // reduce batch2
#pragma unroll
    for (int i = 0; i < 8; ++i){
      float v = sum64(dot4(gA[i], y4));
      if (j == 63) dxax[32 * wu + 16 + i] = v;
    }
    // reduce batch3
#pragma unroll
    for (int i = 0; i < 8; ++i){
      float v = sum64(dot4(gB[i], y4));
      if (j == 63) dxax[32 * wu + 24 + i] = v;
    }
  }
  __syncthreads();                      // raw dx logits visible

  // ---- distributed softmax-128: every wave computes M,S via DPP -----------
  float smM, smInv;
  {
    float a0 = dxax[j], a1 = dxax[j + 64];
    smM = rdlane(max64(fmaxf(a0, a1)), 63);
    float S = rdlane(sum64(__expf(a0 - smM) + __expf(a1 - smM)), 63);
    smInv = 1.f / S;
  }

  // ---- z steady state: 2-buffer rotation; ax normalized inline ------------
  {
    float4 axr[4];
    axr[0] = smx4(*(const float4*)(dxax +      4 * q), smM, smInv);
    axr[1] = smx4(*(const float4*)(dxax + 32 + 4 * q), smM, smInv);
    axr[2] = smx4(*(const float4*)(dxax + 64 + 4 * q), smM, smInv);
    axr[3] = smx4(*(const float4*)(dxax + 96 + 4 * q), smM, smInv);
    float v;
    v = sum8(z_red(za, axr)); if (q == 0) zsm[d2c[0]] = v;
    z_load(za, word_emb, hrowl, d2c[2], q);
    v = sum8(z_red(zb, axr)); if (q == 0) zsm[d2c[1]] = v;
    z_load(zb, word_emb, hrowl, d2c[3], q);
    v = sum8(z_red(za, axr)); if (q == 0) zsm[d2c[2]] = v;
    z_load(za, word_emb, hrowl, d2c[4], q);
    v = sum8(z_red(zb, axr)); if (q == 0) zsm[d2c[3]] = v;
    z_load(zb, word_emb, hrowl, d2c[5], q);
    v = sum8(z_red(za, axr)); if (q == 0) zsm[d2c[4]] = v;
    z_load(za, word_emb, hrowl, d2c[6], q);
    v = sum8(z_red(zb, axr)); if (q == 0) zsm[d2c[5]] = v;
    v = sum8(z_red(za, axr)); if (q == 0 && oct < 2) zsm[d2c[6]] = v;
  }
  __syncthreads();

  // ---- aspect logits: wave w computes a = w*8..w*8+7 ----------------------
#pragma unroll
  for (int aa = 0; aa < 8; ++aa){
    int a = wu * 8 + aa;
    const float* Wr = W_w + a * DD;
    float p = zsm[j] * Wr[j] + zsm[j + 64] * Wr[j + 64] + zsm[j + 128] * Wr[j + 128];
    if (j < 8) p += zsm[j + 192] * Wr[j + 192];
    float v = sum64(p);
    if (j == 63) lsps[a] = v + W_b[a];
  }

  // ---- Tq prefetch: T_w rows issued before the softmax-32 barriers --------
  float4 Tq[8];
  if (t < DD){
    const float4* Tp = (const float4*)(T_w + t * AA);
#pragma unroll
    for (int q8 = 0; q8 < 8; ++q8) Tq[q8] = Tp[q8];
  }
  __syncthreads();

  // ---- softmax over 32 aspects (wave 0) -----------------------------------
  if (w == 0){
    float v = (j < 32) ? lsps[j] : -3.0e38f;
    float M = rdlane(max64(v), 63);
    float e = __expf(v - M);
    float S = rdlane(sum64(e), 63);
    if (j < 32) lsps[j] = e / S;
  }
  __syncthreads();

  // ---- r_s[d] = sum_a p[a]*T_w[d][a] (Tq already in registers) ------------
  if (t < DD){
    float a = 0.f;
#pragma unroll
    for (int q8 = 0; q8 < 8; ++q8){
      float4 tv = Tq[q8];
      a += lsps[4*q8]*tv.x + lsps[4*q8+1]*tv.y + lsps[4*q8+2]*tv.z + lsps[4*q8+3]*tv.w;
    }
    r_l[t] = a;
    rs_out[(size_t)n * DD + t] = a;
  }
  __syncthreads();

  // ---- c1 = cos(r, z) (wave 0, float4) ------------------------------------
  if (w == 0){
    float rr = 0, zz = 0, rz = 0;
    if (j < 50){
      float4 rv = *(float4*)(r_l + 4 * j);
      float4 zv = *(float4*)(zsm + 4 * j);
      rr = dot4(rv, rv); zz = dot4(zv, zv); rz = dot4(rv, zv);
    }
    rr = rdlane(sum64(rr), 63); zz = rdlane(sum64(zz), 63); rz = rdlane(sum64(rz), 63);
    if (j == 0){
      float nr = fmaxf(sqrtf(rr), 1e-12f);
      float nz = fmaxf(sqrtf(zz), 1e-12f);
      sc[0] = rz / (nr * nz);          // c1
      sc[1] = nr;
    }
  }
  __syncthreads();

  // ---- c2 over 5 negatives (waves 0..3; wave 0 also #4), float4 -----------
  for (int g5 = w; g5 < NEG; g5 += 4){
    const float* neg = rev_neg + ((size_t)n * NEG + g5) * DD;
    float nn = 0, dr = 0;
    if (j < 50){
      float4 v = *(const float4*)(neg + 4 * j);
      float4 rv = *(float4*)(r_l + 4 * j);
      nn = dot4(v, v); dr = dot4(v, rv);
    }
    nn = rdlane(sum64(nn), 63); dr = rdlane(sum64(dr), 63);
    if (j == 0){
      float c2 = dr / (fmaxf(sqrtf(nn), 1e-12f) * sc[1]);
      sc[2 + g5] = fmaxf(0.f, c2 - sc[0]);
    }
  }
  __syncthreads();
  if (t == 0) atomicAdd(&acc[0], sc[2] + sc[3] + sc[4] + sc[5] + sc[6]);
}

// ---- finalize helper -------------------------------------------------------
__device__ __forceinline__ void finalize(float* acc, float* out){
  float R = atomicAdd(&acc[2], 0.f) / (float)BB;        // coherent reads
  float J = atomicAdd(&acc[0], 0.f) / (float)(NN * NEG);
  float U = atomicAdd(&acc[1], 0.f);
  out[0] = R + U + J;
  out[1] = R;
  out[2] = U + J;
}

// ---- tail: blocks 0..BB-1 = segment-mean + rating; block BB = U loss -------
// seg ids are repeat(arange(B), H=16): block b owns entries [16b,16b+16).
__global__ __launch_bounds__(256)
void k_tail(const int* __restrict__ u_idx, const int* __restrict__ i_idx,
            const float* __restrict__ rs, const float* __restrict__ label,
            const float* __restrict__ T_w, float* __restrict__ acc,
            float* __restrict__ out){
  __shared__ __align__(16) float smem[6500];
  const int b = blockIdx.x, t = threadIdx.x, w = t >> 6, j = t & 63;

  if (b == BB){
    // ================= U loss =================
    float* Tl  = smem;          // [32][202]
    float* nrm = smem + 6464;
    float* wred= smem + 6496;
    for (int i = t; i < DD * AA; i += 256){
      int d = i >> 5, a = i & 31;
      Tl[a * 202 + d] = T_w[i];
    }
    __syncthreads();
    if (t < AA){
      float s = 0.f;
      for (int d = 0; d < DD; d += 2){
        float2 v = *(float2*)&Tl[t * 202 + d];
        s += v.x * v.x + v.y * v.y;
      }
      nrm[t] = fmaxf(sqrtf(s), 1e-12f);
    }
    __syncthreads();
    int a = t >> 3, b0 = (t & 7) * 4;
    float d0 = 0, d1 = 0, d2 = 0, d3 = 0;
    for (int d = 0; d < DD; d += 2){
      float2 va = *(float2*)&Tl[a * 202 + d];
      float2 v0 = *(float2*)&Tl[(b0    ) * 202 + d];
      float2 v1 = *(float2*)&Tl[(b0 + 1) * 202 + d];
      float2 v2 = *(float2*)&Tl[(b0 + 2) * 202 + d];
      float2 v3 = *(float2*)&Tl[(b0 + 3) * 202 + d];
      d0 += va.x * v0.x + va.y * v0.y;
      d1 += va.x * v1.x + va.y * v1.y;
      d2 += va.x * v2.x + va.y * v2.y;
      d3 += va.x * v3.x + va.y * v3.y;
    }
    float na = nrm[a], gg = 0.f, g;
    g = d0 / (na * nrm[b0    ]) - (a == b0     ? 1.f : 0.f); gg += g * g;
    g = d1 / (na * nrm[b0 + 1]) - (a == b0 + 1 ? 1.f : 0.f); gg += g * g;
    g = d2 / (na * nrm[b0 + 2]) - (a == b0 + 2 ? 1.f : 0.f); gg += g * g;
    g = d3 / (na * nrm[b0 + 3]) - (a == b0 + 3 ? 1.f : 0.f); gg += g * g;
    float v = sum64(gg);
    if (j == 63) wred[w] = v;
    __syncthreads();
    if (t == 0){
      atomicAdd(&acc[1], (wred[0] + wred[1] + wred[2] + wred[3]) / (float)(AA * AA));
      __threadfence();
      int prev = atomicAdd((int*)acc + 8, 1);
      if (prev == BB) finalize(acc, out);
    }
    return;
  }

  // ================= segment-mean + rating =================
  int*   idxs = (int*)smem;        // 32
  float* wred = smem + 32;         // 4
  if (t < 16) idxs[t] = u_idx[b * 16 + t];
  else if (t < 32) idxs[t] = i_idx[b * 16 + (t - 16)];
  __syncthreads();
  float su = 0.f, si = 0.f;
  if (t < DD){
#pragma unroll
    for (int k = 0; k < 16; ++k) su += rs[(size_t)idxs[k] * DD + t];
#pragma unroll
    for (int k = 0; k < 16; ++k) si += rs[(size_t)idxs[16 + k] * DD + t];
  }
  float v = sum64(su * si);
  if (j == 63) wred[w] = v;
  __syncthreads();
  if (t == 0){
    float dot = wred[0] + wred[1] + wred[2] + wred[3];
    float pred = dot * (1.f / 256.f) + 3.5f;     // /16 /16
    float e = pred - label[b];
    atomicAdd(&acc[2], e * e);
    __threadfence();
    int prev = atomicAdd((int*)acc + 8, 1);
    if (prev == BB) finalize(acc, out);
  }
}

extern "C" void kernel_launch(void* const* d_in, const int* in_sizes, int n_in,
                              void* d_out, int out_size, void* d_ws, size_t ws_size,
                              hipStream_t stream){
  const int*   hist     = (const int*)  d_in[0];
  const float* rev_pos  = (const float*)d_in[1];
  const float* rev_neg  = (const float*)d_in[2];
  const float* label    = (const float*)d_in[5];
  const int*   u_idx    = (const int*)  d_in[6];
  const int*   i_idx    = (const int*)  d_in[8];
  const float* word_emb = (const float*)d_in[10];
  const float* M_w      = (const float*)d_in[11];
  const float* W_w      = (const float*)d_in[12];
  const float* W_b      = (const float*)d_in[13];
  const float* T_w      = (const float*)d_in[14];

  float* ws   = (float*)d_ws;
  float* rs   = ws + WS_RS;
  float* accp = ws + WS_ACC;

  hipMemsetAsync(accp, 0, 64, stream);   // zero J/U/RL accumulators + counter
  k_main<<<NN, 256, 0, stream>>>(hist, rev_pos, rev_neg, word_emb, M_w,
                                 W_w, W_b, T_w, rs, accp);
  k_tail<<<BB + 1, 256, 0, stream>>>(u_idx, i_idx, rs, label, T_w, accp,
                                     (float*)d_out);
}

// Round 10
// 287.697 us; speedup vs baseline: 1.2427x; 1.2427x over previous
//
#include <hip/hip_runtime.h>

#define NN 4096      // reviews
#define LL 128       // tokens
#define DD 200       // word dim
#define AA 32        // aspects
#define NEG 5
#define BB 1024      // users/items

// workspace layout (float offsets)
#define WS_RS    0
#define WS_ACC   (NN*DD)   // [0]=J_sum [1]=U_mean [2]=RL_sum [8]=done(int)

// ---------------- DPP reductions (VALU, no DS pipe) -------------------------
template<int C, int RM>
__device__ __forceinline__ float dpp_add(float v){
  int t = __builtin_amdgcn_update_dpp(0, __float_as_int(v), C, RM, 0xf, false);
  return v + __int_as_float(t);
}
template<int C, int RM>
__device__ __forceinline__ float dpp_fmax(float v){
  int t = __builtin_amdgcn_update_dpp(__float_as_int(-3.0e38f), __float_as_int(v),
                                      C, RM, 0xf, false);
  return fmaxf(v, __int_as_float(t));
}
// full 64-lane sum; valid in lane 63
__device__ __forceinline__ float sum64(float v){
  v = dpp_add<0xB1, 0xF>(v);
  v = dpp_add<0x4E, 0xF>(v);
  v = dpp_add<0x124,0xF>(v);
  v = dpp_add<0x128,0xF>(v);
  v = dpp_add<0x142,0xA>(v);
  v = dpp_add<0x143,0xC>(v);
  return v;
}
__device__ __forceinline__ float max64(float v){
  v = dpp_fmax<0xB1, 0xF>(v);
  v = dpp_fmax<0x4E, 0xF>(v);
  v = dpp_fmax<0x124,0xF>(v);
  v = dpp_fmax<0x128,0xF>(v);
  v = dpp_fmax<0x142,0xA>(v);
  v = dpp_fmax<0x143,0xC>(v);
  return v;
}
// 8-lane (octet) sum: valid at lanes j%8==0
__device__ __forceinline__ float sum8(float v){
  v = dpp_add<0xB1, 0xF>(v);
  v = dpp_add<0x4E, 0xF>(v);
  v = dpp_add<0x124,0xF>(v);
  return v;
}
__device__ __forceinline__ float rdlane(float v, int l){
  return __int_as_float(__builtin_amdgcn_readlane(__float_as_int(v), l));
}
__device__ __forceinline__ float dot4(float4 a, float4 b){
  return a.x*b.x + a.y*b.y + a.z*b.z + a.w*b.w;
}
__device__ __forceinline__ float4 smx4(float4 r, float M, float invS){
  float4 o;
  o.x = __expf(r.x - M) * invS; o.y = __expf(r.y - M) * invS;
  o.z = __expf(r.z - M) * invS; o.w = __expf(r.w - M) * invS;
  return o;
}

// z-pass helpers: octet (8 lanes) per d2, lane q covers l2 = 32i+4q..+3
__device__ __forceinline__ void z_load(float4* buf, const float* __restrict__ we,
                                       const int* hrowl, int d2, int q){
  unsigned f0 = (unsigned)d2 * 128u + 4u * (unsigned)q;
#pragma unroll
  for (int i = 0; i < 4; ++i){
    unsigned f = f0 + 32u * i;
    unsigned r = f / 200u;
    buf[i] = *(const float4*)(we + (size_t)hrowl[r] * DD + (f - r * 200u));
  }
}
__device__ __forceinline__ float z_red(const float4* buf, const float4* ax){
  return dot4(buf[0],ax[0]) + dot4(buf[1],ax[1]) + dot4(buf[2],ax[2]) + dot4(buf[3],ax[3]);
}

// ---- main per-review kernel ------------------------------------------------
// LDS (floats): y_l[0,200) dxax[208,336) zsm[336,536) r_l[536,736)
//               lsps[736,768) sc[768,776) hrowl(int)[776,904) ypart[904,1704)
__global__ __launch_bounds__(256, 7)
void k_main(const int* __restrict__ hist, const float* __restrict__ rev_pos,
            const float* __restrict__ rev_neg, const float* __restrict__ word_emb,
            const float* __restrict__ M_w, const float* __restrict__ W_w,
            const float* __restrict__ W_b, const float* __restrict__ T_w,
            float* __restrict__ rs_out, float* __restrict__ acc)
{
  __shared__ __align__(16) float smem[1704];
  float* y_l  = smem;
  float* dxax = smem + 208;
  float* zsm  = smem + 336;
  float* r_l  = smem + 536;   // holds rp first, r_s later
  float* lsps = smem + 736;
  float* sc   = smem + 768;
  int*   hrowl= (int*)(smem + 776);
  float* ypart= smem + 904;

  const int n = blockIdx.x;
  const int t = threadIdx.x;
  const int w = t >> 6, j = t & 63;
  const int wu = __builtin_amdgcn_readfirstlane(w);

  if (t < DD) r_l[t] = rev_pos[(size_t)n * DD + t];
  if (t < LL) hrowl[t] = hist[(size_t)n * LL + t];
  __syncthreads();

  // ---- y = rp @ M, split-K across waves: wave w covers d in [50w,50w+50) --
  if (j < 50){
    float ax = 0.f, ay = 0.f, az = 0.f, aw = 0.f;
    const float* Mb = M_w + (50 * wu) * DD + 4 * j;
    const float* rb = r_l + 50 * wu;
#pragma unroll 10
    for (int dk = 0; dk < 50; ++dk){
      float rv = rb[dk];
      float4 m4 = *(const float4*)(Mb + dk * DD);
      ax = fmaf(rv, m4.x, ax); ay = fmaf(rv, m4.y, ay);
      az = fmaf(rv, m4.z, az); aw = fmaf(rv, m4.w, aw);
    }
    float4 o; o.x = ax; o.y = ay; o.z = az; o.w = aw;
    *(float4*)(ypart + wu * 200 + 4 * j) = o;
  }
  __syncthreads();
  if (t < DD) y_l[t] = ypart[t] + ypart[200 + t] + ypart[400 + t] + ypart[600 + t];
  __syncthreads();

  // ---- dx[l]: wave w owns rows [32w,32w+32); SGPR row ids; 8-deep batches -
  const int q = j & 7, oct = j >> 3;
  int d2c[7];
#pragma unroll
  for (int k = 0; k < 7; ++k){
    int off = 8 * k + oct;
    d2c[k] = 50 * wu + (off < 50 ? off : 49);   // clamp; store guarded later
  }
  {
    float4 y4 = make_float4(0.f, 0.f, 0.f, 0.f);
    int col = 0;
    if (j < 50){ y4 = *(const float4*)(y_l + 4 * j); col = 4 * j; }
    const int* hrow_g = hist + (size_t)n * LL + 32 * wu;   // wave-uniform base
    int rA[8], rB[8];
    float4 gA[8], gB[8];
    // load batch0, batch1
#pragma unroll
    for (int i = 0; i < 8; ++i) rA[i] = hrow_g[i];         // s_load
#pragma unroll
    for (int i = 0; i < 8; ++i)
      gA[i] = *(const float4*)(word_emb + (size_t)rA[i] * DD + col);
#pragma unroll
    for (int i = 0; i < 8; ++i) rB[i] = hrow_g[8 + i];
#pragma unroll
    for (int i = 0; i < 8; ++i)
      gB[i] = *(const float4*)(word_emb + (size_t)rB[i] * DD + col);
    // reduce batch0
#pragma unroll
    for (int i = 0; i < 8; ++i){
      float v = sum64(dot4(gA[i], y4));
      if (j == 63) dxax[32 * wu + i] = v;
    }
    // load batch2
#pragma unroll
    for (int i = 0; i < 8; ++i) rA[i] = hrow_g[16 + i];
#pragma unroll
    for (int i = 0; i < 8; ++i)
      gA[i] = *(const float4*)(word_emb + (size_t)rA[i] * DD + col);
    // reduce batch1
#pragma unroll
    for (int i = 0; i < 8; ++i){
      float v = sum64(dot4(gB[i], y4));
      if (j == 63) dxax[32 * wu + 8 + i] = v;
    }
    // load batch3
#pragma unroll
    for (int i = 0; i < 8; ++i) rB[i] = hrow_g[24 + i];
#pragma unroll
    for (int i = 0; i < 8; ++i)
      gB[i] = *(const float4*)(word_emb + (size_t)rB[i] * DD + col);
    // reduce batch2
#pragma unroll
    for (int i = 0; i < 8; ++i){
      float v = sum64(dot4(gA[i], y4));
      if (j == 63) dxax[32 * wu + 16 + i] = v;
    }
    // reduce batch3
#pragma unroll
    for (int i = 0; i < 8; ++i){
      float v = sum64(dot4(gB[i], y4));
      if (j == 63) dxax[32 * wu + 24 + i] = v;
    }
  }

  // ---- z prologue: gA/gB now dead; issue iters 0,1 before the barrier -----
  float4 za[4], zb[4];
  z_load(za, word_emb, hrowl, d2c[0], q);
  z_load(zb, word_emb, hrowl, d2c[1], q);

  __syncthreads();                      // raw dx logits visible

  // ---- distributed softmax-128: every wave computes M,S via DPP -----------
  // (za/zb loads fly underneath; all 64 lanes participate — no guard)
  float smM, smInv;
  {
    float a0 = dxax[j], a1 = dxax[j + 64];
    smM = rdlane(max64(fmaxf(a0, a1)), 63);
    float S = rdlane(sum64(__expf(a0 - smM) + __expf(a1 - smM)), 63);
    smInv = 1.f / S;
  }

  // ---- z steady state: 2-buffer rotation; ax normalized inline ------------
  {
    float4 axr[4];
    axr[0] = smx4(*(const float4*)(dxax +      4 * q), smM, smInv);
    axr[1] = smx4(*(const float4*)(dxax + 32 + 4 * q), smM, smInv);
    axr[2] = smx4(*(const float4*)(dxax + 64 + 4 * q), smM, smInv);
    axr[3] = smx4(*(const float4*)(dxax + 96 + 4 * q), smM, smInv);
    float v;
    v = sum8(z_red(za, axr)); if (q == 0) zsm[d2c[0]] = v;
    z_load(za, word_emb, hrowl, d2c[2], q);
    v = sum8(z_red(zb, axr)); if (q == 0) zsm[d2c[1]] = v;
    z_load(zb, word_emb, hrowl, d2c[3], q);
    v = sum8(z_red(za, axr)); if (q == 0) zsm[d2c[2]] = v;
    z_load(za, word_emb, hrowl, d2c[4], q);
    v = sum8(z_red(zb, axr)); if (q == 0) zsm[d2c[3]] = v;
    z_load(zb, word_emb, hrowl, d2c[5], q);
    v = sum8(z_red(za, axr)); if (q == 0) zsm[d2c[4]] = v;
    z_load(za, word_emb, hrowl, d2c[6], q);
    v = sum8(z_red(zb, axr)); if (q == 0) zsm[d2c[5]] = v;
    v = sum8(z_red(za, axr)); if (q == 0 && oct < 2) zsm[d2c[6]] = v;
  }
  __syncthreads();

  // ---- aspect logits (raw, + bias): wave w computes a = w*8..w*8+7 --------
#pragma unroll
  for (int aa = 0; aa < 8; ++aa){
    int a = wu * 8 + aa;
    const float* Wr = W_w + a * DD;
    float p = zsm[j] * Wr[j] + zsm[j + 64] * Wr[j + 64] + zsm[j + 128] * Wr[j + 128];
    if (j < 8) p += zsm[j + 192] * Wr[j + 192];
    float v = sum64(p);
    if (j == 63) lsps[a] = v + W_b[a];
  }
  __syncthreads();                      // raw aspect logits visible

  // ---- distributed softmax-32 stats (all lanes participate — no guard) ----
  float aM, aInv;
  {
    float v = (j < 32) ? lsps[j] : -3.0e38f;
    aM = rdlane(max64(v), 63);
    float e = (j < 32) ? __expf(v - aM) : 0.f;
    aInv = 1.f / rdlane(sum64(e), 63);
  }

  // ---- r_s[d] = sum_a softmax(lsps)[a]*T_w[d][a] (T_w L1-hot) -------------
  if (t < DD){
    const float4* Tp = (const float4*)(T_w + t * AA);
    float a = 0.f;
#pragma unroll
    for (int q8 = 0; q8 < 8; ++q8){
      float4 tv = Tp[q8];
      a += __expf(lsps[4*q8    ] - aM) * aInv * tv.x;
      a += __expf(lsps[4*q8 + 1] - aM) * aInv * tv.y;
      a += __expf(lsps[4*q8 + 2] - aM) * aInv * tv.z;
      a += __expf(lsps[4*q8 + 3] - aM) * aInv * tv.w;
    }
    r_l[t] = a;
    rs_out[(size_t)n * DD + t] = a;
  }
  __syncthreads();

  // ---- c1 = cos(r, z) (wave 0, float4) ------------------------------------
  if (w == 0){
    float rr = 0, zz = 0, rz = 0;
    if (j < 50){
      float4 rv = *(float4*)(r_l + 4 * j);
      float4 zv = *(float4*)(zsm + 4 * j);
      rr = dot4(rv, rv); zz = dot4(zv, zv); rz = dot4(rv, zv);
    }
    rr = rdlane(sum64(rr), 63); zz = rdlane(sum64(zz), 63); rz = rdlane(sum64(rz), 63);
    if (j == 0){
      float nr = fmaxf(sqrtf(rr), 1e-12f);
      float nz = fmaxf(sqrtf(zz), 1e-12f);
      sc[0] = rz / (nr * nz);          // c1
      sc[1] = nr;
    }
  }
  __syncthreads();

  // ---- c2 over 5 negatives (waves 0..3; wave 0 also #4), float4 -----------
  for (int g5 = w; g5 < NEG; g5 += 4){
    const float* neg = rev_neg + ((size_t)n * NEG + g5) * DD;
    float nn = 0, dr = 0;
    if (j < 50){
      float4 v = *(const float4*)(neg + 4 * j);
      float4 rv = *(float4*)(r_l + 4 * j);
      nn = dot4(v, v); dr = dot4(v, rv);
    }
    nn = rdlane(sum64(nn), 63); dr = rdlane(sum64(dr), 63);
    if (j == 0){
      float c2 = dr / (fmaxf(sqrtf(nn), 1e-12f) * sc[1]);
      sc[2 + g5] = fmaxf(0.f, c2 - sc[0]);
    }
  }
  __syncthreads();
  if (t == 0) atomicAdd(&acc[0], sc[2] + sc[3] + sc[4] + sc[5] + sc[6]);
}

// ---- finalize helper -------------------------------------------------------
__device__ __forceinline__ void finalize(float* acc, float* out){
  float R = atomicAdd(&acc[2], 0.f) / (float)BB;        // coherent reads
  float J = atomicAdd(&acc[0], 0.f) / (float)(NN * NEG);
  float U = atomicAdd(&acc[1], 0.f);
  out[0] = R + U + J;
  out[1] = R;
  out[2] = U + J;
}

// ---- tail: blocks 0..BB-1 = segment-mean + rating; block BB = U loss -------
// seg ids are repeat(arange(B), H=16): block b owns entries [16b,16b+16).
__global__ __launch_bounds__(256)
void k_tail(const int* __restrict__ u_idx, const int* __restrict__ i_idx,
            const float* __restrict__ rs, const float* __restrict__ label,
            const float* __restrict__ T_w, float* __restrict__ acc,
            float* __restrict__ out){
  __shared__ __align__(16) float smem[6500];
  const int b = blockIdx.x, t = threadIdx.x, w = t >> 6, j = t & 63;

  if (b == BB){
    // ================= U loss =================
    float* Tl  = smem;          // [32][202]
    float* nrm = smem + 6464;
    float* wred= smem + 6496;
    for (int i = t; i < DD * AA; i += 256){
      int d = i >> 5, a = i & 31;
      Tl[a * 202 + d] = T_w[i];
    }
    __syncthreads();
    if (t < AA){
      float s = 0.f;
      for (int d = 0; d < DD; d += 2){
        float2 v = *(float2*)&Tl[t * 202 + d];
        s += v.x * v.x + v.y * v.y;
      }
      nrm[t] = fmaxf(sqrtf(s), 1e-12f);
    }
    __syncthreads();
    int a = t >> 3, b0 = (t & 7) * 4;
    float d0 = 0, d1 = 0, d2 = 0, d3 = 0;
    for (int d = 0; d < DD; d += 2){
      float2 va = *(float2*)&Tl[a * 202 + d];
      float2 v0 = *(float2*)&Tl[(b0    ) * 202 + d];
      float2 v1 = *(float2*)&Tl[(b0 + 1) * 202 + d];
      float2 v2 = *(float2*)&Tl[(b0 + 2) * 202 + d];
      float2 v3 = *(float2*)&Tl[(b0 + 3) * 202 + d];
      d0 += va.x * v0.x + va.y * v0.y;
      d1 += va.x * v1.x + va.y * v1.y;
      d2 += va.x * v2.x + va.y * v2.y;
      d3 += va.x * v3.x + va.y * v3.y;
    }
    float na = nrm[a], gg = 0.f, g;
    g = d0 / (na * nrm[b0    ]) - (a == b0     ? 1.f : 0.f); gg += g * g;
    g = d1 / (na * nrm[b0 + 1]) - (a == b0 + 1 ? 1.f : 0.f); gg += g * g;
    g = d2 / (na * nrm[b0 + 2]) - (a == b0 + 2 ? 1.f : 0.f); gg += g * g;
    g = d3 / (na * nrm[b0 + 3]) - (a == b0 + 3 ? 1.f : 0.f); gg += g * g;
    float v = sum64(gg);
    if (j == 63) wred[w] = v;
    __syncthreads();
    if (t == 0){
      atomicAdd(&acc[1], (wred[0] + wred[1] + wred[2] + wred[3]) / (float)(AA * AA));
      __threadfence();
      int prev = atomicAdd((int*)acc + 8, 1);
      if (prev == BB) finalize(acc, out);
    }
    return;
  }

  // ================= segment-mean + rating =================
  int*   idxs = (int*)smem;        // 32
  float* wred = smem + 32;         // 4
  if (t < 16) idxs[t] = u_idx[b * 16 + t];
  else if (t < 32) idxs[t] = i_idx[b * 16 + (t - 16)];
  __syncthreads();
  float su = 0.f, si = 0.f;
  if (t < DD){
#pragma unroll
    for (int k = 0; k < 16; ++k) su += rs[(size_t)idxs[k] * DD + t];
#pragma unroll
    for (int k = 0; k < 16; ++k) si += rs[(size_t)idxs[16 + k] * DD + t];
  }
  float v = sum64(su * si);
  if (j == 63) wred[w] = v;
  __syncthreads();
  if (t == 0){
    float dot = wred[0] + wred[1] + wred[2] + wred[3];
    float pred = dot * (1.f / 256.f) + 3.5f;     // /16 /16
    float e = pred - label[b];
    atomicAdd(&acc[2], e * e);
    __threadfence();
    int prev = atomicAdd((int*)acc + 8, 1);
    if (prev == BB) finalize(acc, out);
  }
}

extern "C" void kernel_launch(void* const* d_in, const int* in_sizes, int n_in,
                              void* d_out, int out_size, void* d_ws, size_t ws_size,
                              hipStream_t stream){
  const int*   hist     = (const int*)  d_in[0];
  const float* rev_pos  = (const float*)d_in[1];
  const float* rev_neg  = (const float*)d_in[2];
  const float* label    = (const float*)d_in[5];
  const int*   u_idx    = (const int*)  d_in[6];
  const int*   i_idx    = (const int*)  d_in[8];
  const float* word_emb = (const float*)d_in[10];
  const float* M_w      = (const float*)d_in[11];
  const float* W_w      = (const float*)d_in[12];
  const float* W_b      = (const float*)d_in[13];
  const float* T_w      = (const float*)d_in[14];

  float* ws   = (float*)d_ws;
  float* rs   = ws + WS_RS;
  float* accp = ws + WS_ACC;

  hipMemsetAsync(accp, 0, 64, stream);   // zero J/U/RL accumulators + counter
  k_main<<<NN, 256, 0, stream>>>(hist, rev_pos, rev_neg, word_emb, M_w,
                                 W_w, W_b, T_w, rs, accp);
  k_tail<<<BB + 1, 256, 0, stream>>>(u_idx, i_idx, rs, label, T_w, accp,
                                     (float*)d_out);
}

// Round 11
// 287.560 us; speedup vs baseline: 1.2432x; 1.0005x over previous
//
#include <hip/hip_runtime.h>

#define NN 4096      // reviews
#define LL 128       // tokens
#define DD 200       // word dim
#define AA 32        // aspects
#define NEG 5
#define BB 1024      // users/items

// workspace layout (float offsets)
#define WS_RS    0
#define WS_ACC   (NN*DD)   // [0]=J_sum [1]=U_mean [2]=RL_sum [8]=done(int)

// ---------------- DPP reductions (VALU, no DS pipe) -------------------------
template<int C, int RM>
__device__ __forceinline__ float dpp_add(float v){
  int t = __builtin_amdgcn_update_dpp(0, __float_as_int(v), C, RM, 0xf, false);
  return v + __int_as_float(t);
}
template<int C, int RM>
__device__ __forceinline__ float dpp_fmax(float v){
  int t = __builtin_amdgcn_update_dpp(__float_as_int(-3.0e38f), __float_as_int(v),
                                      C, RM, 0xf, false);
  return fmaxf(v, __int_as_float(t));
}
// full 64-lane sum; valid in lane 63
__device__ __forceinline__ float sum64(float v){
  v = dpp_add<0xB1, 0xF>(v);
  v = dpp_add<0x4E, 0xF>(v);
  v = dpp_add<0x124,0xF>(v);
  v = dpp_add<0x128,0xF>(v);
  v = dpp_add<0x142,0xA>(v);
  v = dpp_add<0x143,0xC>(v);
  return v;
}
__device__ __forceinline__ float max64(float v){
  v = dpp_fmax<0xB1, 0xF>(v);
  v = dpp_fmax<0x4E, 0xF>(v);
  v = dpp_fmax<0x124,0xF>(v);
  v = dpp_fmax<0x128,0xF>(v);
  v = dpp_fmax<0x142,0xA>(v);
  v = dpp_fmax<0x143,0xC>(v);
  return v;
}
// 8-lane (octet) sum: valid at lanes j%8==0
__device__ __forceinline__ float sum8(float v){
  v = dpp_add<0xB1, 0xF>(v);
  v = dpp_add<0x4E, 0xF>(v);
  v = dpp_add<0x124,0xF>(v);
  return v;
}
__device__ __forceinline__ float rdlane(float v, int l){
  return __int_as_float(__builtin_amdgcn_readlane(__float_as_int(v), l));
}
__device__ __forceinline__ float dot4(float4 a, float4 b){
  return a.x*b.x + a.y*b.y + a.z*b.z + a.w*b.w;
}

// z-pass helpers: octet (8 lanes) per d2, lane q covers l2 = 32i+4q..+3
__device__ __forceinline__ void z_load(float4* buf, const float* __restrict__ we,
                                       const int* hrowl, int d2, int q){
  unsigned f0 = (unsigned)d2 * 128u + 4u * (unsigned)q;
#pragma unroll
  for (int i = 0; i < 4; ++i){
    unsigned f = f0 + 32u * i;
    unsigned r = f / 200u;
    buf[i] = *(const float4*)(we + (size_t)hrowl[r] * DD + (f - r * 200u));
  }
}
__device__ __forceinline__ float z_red(const float4* buf, const float4* ax){
  return dot4(buf[0],ax[0]) + dot4(buf[1],ax[1]) + dot4(buf[2],ax[2]) + dot4(buf[3],ax[3]);
}

// ---- main per-review kernel ------------------------------------------------
// LDS (floats): y_l[0,200) dxax[208,336) zsm[336,536) r_l[536,736)
//               lsps[736,768) sc[768,776) hrowl(int)[776,904) ypart[904,1704)
__global__ __launch_bounds__(256, 7)
void k_main(const int* __restrict__ hist, const float* __restrict__ rev_pos,
            const float* __restrict__ rev_neg, const float* __restrict__ word_emb,
            const float* __restrict__ M_w, const float* __restrict__ W_w,
            const float* __restrict__ W_b, const float* __restrict__ T_w,
            float* __restrict__ rs_out, float* __restrict__ acc)
{
  __shared__ __align__(16) float smem[1704];
  float* y_l  = smem;
  float* dxax = smem + 208;
  float* zsm  = smem + 336;
  float* r_l  = smem + 536;   // holds rp first, r_s later
  float* lsps = smem + 736;
  float* sc   = smem + 768;
  int*   hrowl= (int*)(smem + 776);
  float* ypart= smem + 904;

  const int n = blockIdx.x;
  const int t = threadIdx.x;
  const int w = t >> 6, j = t & 63;
  const int wu = __builtin_amdgcn_readfirstlane(w);

  if (t < DD) r_l[t] = rev_pos[(size_t)n * DD + t];
  if (t < LL) hrowl[t] = hist[(size_t)n * LL + t];
  __syncthreads();

  // ---- y = rp @ M, split-K across waves: wave w covers d in [50w,50w+50) --
  if (j < 50){
    float ax = 0.f, ay = 0.f, az = 0.f, aw = 0.f;
    const float* Mb = M_w + (50 * wu) * DD + 4 * j;
    const float* rb = r_l + 50 * wu;
#pragma unroll 10
    for (int dk = 0; dk < 50; ++dk){
      float rv = rb[dk];
      float4 m4 = *(const float4*)(Mb + dk * DD);
      ax = fmaf(rv, m4.x, ax); ay = fmaf(rv, m4.y, ay);
      az = fmaf(rv, m4.z, az); aw = fmaf(rv, m4.w, aw);
    }
    float4 o; o.x = ax; o.y = ay; o.z = az; o.w = aw;
    *(float4*)(ypart + wu * 200 + 4 * j) = o;
  }
  __syncthreads();
  if (t < DD) y_l[t] = ypart[t] + ypart[200 + t] + ypart[400 + t] + ypart[600 + t];
  __syncthreads();

  // ---- dx[l]: wave w owns rows [32w,32w+32); SGPR row ids; 8-deep batches -
  const int q = j & 7, oct = j >> 3;
  int d2c[7];
#pragma unroll
  for (int k = 0; k < 7; ++k){
    int off = 8 * k + oct;
    d2c[k] = 50 * wu + (off < 50 ? off : 49);   // clamp; store guarded later
  }
  {
    float4 y4 = make_float4(0.f, 0.f, 0.f, 0.f);
    int col = 0;
    if (j < 50){ y4 = *(const float4*)(y_l + 4 * j); col = 4 * j; }
    const int* hrow_g = hist + (size_t)n * LL + 32 * wu;   // wave-uniform base
    int rA[8], rB[8];
    float4 gA[8], gB[8];
    // load batch0, batch1
#pragma unroll
    for (int i = 0; i < 8; ++i) rA[i] = hrow_g[i];         // s_load
#pragma unroll
    for (int i = 0; i < 8; ++i)
      gA[i] = *(const float4*)(word_emb + (size_t)rA[i] * DD + col);
#pragma unroll
    for (int i = 0; i < 8; ++i) rB[i] = hrow_g[8 + i];
#pragma unroll
    for (int i = 0; i < 8; ++i)
      gB[i] = *(const float4*)(word_emb + (size_t)rB[i] * DD + col);
    // reduce batch0
#pragma unroll
    for (int i = 0; i < 8; ++i){
      float v = sum64(dot4(gA[i], y4));
      if (j == 63) dxax[32 * wu + i] = v;
    }
    // load batch2
#pragma unroll
    for (int i = 0; i < 8; ++i) rA[i] = hrow_g[16 + i];
#pragma unroll
    for (int i = 0; i < 8; ++i)
      gA[i] = *(const float4*)(word_emb + (size_t)rA[i] * DD + col);
    // reduce batch1
#pragma unroll
    for (int i = 0; i < 8; ++i){
      float v = sum64(dot4(gB[i], y4));
      if (j == 63) dxax[32 * wu + 8 + i] = v;
    }
    // load batch3
#pragma unroll
    for (int i = 0; i < 8; ++i) rB[i] = hrow_g[24 + i];
#pragma unroll
    for (int i = 0; i < 8; ++i)
      gB[i] = *(const float4*)(word_emb + (size_t)rB[i] * DD + col);
    // reduce batch2
#pragma unroll
    for (int i = 0; i < 8; ++i){
      float v = sum64(dot4(gA[i], y4));
      if (j == 63) dxax[32 * wu + 16 + i] = v;
    }
    // reduce batch3
#pragma unroll
    for (int i = 0; i < 8; ++i){
      float v = sum64(dot4(gB[i], y4));
      if (j == 63) dxax[32 * wu + 24 + i] = v;
    }
  }

  // ---- z prologue: gA/gB now dead; issue iters 0,1 before the barrier -----
  float4 za[4], zb[4];
  z_load(za, word_emb, hrowl, d2c[0], q);
  z_load(zb, word_emb, hrowl, d2c[1], q);

  __syncthreads();                      // dx logits visible

  // ---- softmax over 128 logits (wave 0); others' z loads fly meanwhile ----
  if (w == 0){
    float a0 = dxax[j], a1 = dxax[j + 64];
    float M = rdlane(max64(fmaxf(a0, a1)), 63);
    float e0 = __expf(a0 - M), e1 = __expf(a1 - M);
    float S = rdlane(sum64(e0 + e1), 63);
    float inv = 1.f / S;
    dxax[j] = e0 * inv; dxax[j + 64] = e1 * inv;
  }
  __syncthreads();

  // ---- z steady state: 2-buffer rotation over 7 octet-iterations ----------
  {
    float4 axr[4];
    axr[0] = *(const float4*)(dxax +      4 * q);
    axr[1] = *(const float4*)(dxax + 32 + 4 * q);
    axr[2] = *(const float4*)(dxax + 64 + 4 * q);
    axr[3] = *(const float4*)(dxax + 96 + 4 * q);
    float v;
    v = sum8(z_red(za, axr)); if (q == 0) zsm[d2c[0]] = v;
    z_load(za, word_emb, hrowl, d2c[2], q);
    v = sum8(z_red(zb, axr)); if (q == 0) zsm[d2c[1]] = v;
    z_load(zb, word_emb, hrowl, d2c[3], q);
    v = sum8(z_red(za, axr)); if (q == 0) zsm[d2c[2]] = v;
    z_load(za, word_emb, hrowl, d2c[4], q);
    v = sum8(z_red(zb, axr)); if (q == 0) zsm[d2c[3]] = v;
    z_load(zb, word_emb, hrowl, d2c[5], q);
    v = sum8(z_red(za, axr)); if (q == 0) zsm[d2c[4]] = v;
    z_load(za, word_emb, hrowl, d2c[6], q);
    v = sum8(z_red(zb, axr)); if (q == 0) zsm[d2c[5]] = v;
    v = sum8(z_red(za, axr)); if (q == 0 && oct < 2) zsm[d2c[6]] = v;
  }
  __syncthreads();

  // ---- aspect logits: wave w computes a = w*8..w*8+7 ----------------------
#pragma unroll
  for (int aa = 0; aa < 8; ++aa){
    int a = wu * 8 + aa;
    const float* Wr = W_w + a * DD;
    float p = zsm[j] * Wr[j] + zsm[j + 64] * Wr[j + 64] + zsm[j + 128] * Wr[j + 128];
    if (j < 8) p += zsm[j + 192] * Wr[j + 192];
    float v = sum64(p);
    if (j == 63) lsps[a] = v + W_b[a];
  }
  __syncthreads();

  // ---- softmax over 32 aspects (wave 0) -----------------------------------
  if (w == 0){
    float v = (j < 32) ? lsps[j] : -3.0e38f;
    float M = rdlane(max64(v), 63);
    float e = __expf(v - M);
    float S = rdlane(sum64(e), 63);
    if (j < 32) lsps[j] = e / S;
  }
  __syncthreads();

  // ---- r_s[d] = sum_a p[a]*T_w[d][a]: lane reads own 128B of T_w ----------
  if (t < DD){
    const float4* Tq = (const float4*)(T_w + t * AA);
    float a = 0.f;
#pragma unroll
    for (int q8 = 0; q8 < 8; ++q8){
      float4 tv = Tq[q8];
      a += lsps[4*q8]*tv.x + lsps[4*q8+1]*tv.y + lsps[4*q8+2]*tv.z + lsps[4*q8+3]*tv.w;
    }
    r_l[t] = a;
    rs_out[(size_t)n * DD + t] = a;
  }
  __syncthreads();

  // ---- c1 = cos(r, z) (wave 0, float4) ------------------------------------
  if (w == 0){
    float rr = 0, zz = 0, rz = 0;
    if (j < 50){
      float4 rv = *(float4*)(r_l + 4 * j);
      float4 zv = *(float4*)(zsm + 4 * j);
      rr = dot4(rv, rv); zz = dot4(zv, zv); rz = dot4(rv, zv);
    }
    rr = rdlane(sum64(rr), 63); zz = rdlane(sum64(zz), 63); rz = rdlane(sum64(rz), 63);
    if (j == 0){
      float nr = fmaxf(sqrtf(rr), 1e-12f);
      float nz = fmaxf(sqrtf(zz), 1e-12f);
      sc[0] = rz / (nr * nz);          // c1
      sc[1] = nr;
    }
  }
  __syncthreads();

  // ---- c2 over 5 negatives (waves 0..3; wave 0 also #4), float4 -----------
  for (int g5 = w; g5 < NEG; g5 += 4){
    const float* neg = rev_neg + ((size_t)n * NEG + g5) * DD;
    float nn = 0, dr = 0;
    if (j < 50){
      float4 v = *(const float4*)(neg + 4 * j);
      float4 rv = *(float4*)(r_l + 4 * j);
      nn = dot4(v, v); dr = dot4(v, rv);
    }
    nn = rdlane(sum64(nn), 63); dr = rdlane(sum64(dr), 63);
    if (j == 0){
      float c2 = dr / (fmaxf(sqrtf(nn), 1e-12f) * sc[1]);
      sc[2 + g5] = fmaxf(0.f, c2 - sc[0]);
    }
  }
  __syncthreads();
  if (t == 0) atomicAdd(&acc[0], sc[2] + sc[3] + sc[4] + sc[5] + sc[6]);
}

// ---- finalize helper -------------------------------------------------------
__device__ __forceinline__ void finalize(float* acc, float* out){
  float R = atomicAdd(&acc[2], 0.f) / (float)BB;        // coherent reads
  float J = atomicAdd(&acc[0], 0.f) / (float)(NN * NEG);
  float U = atomicAdd(&acc[1], 0.f);
  out[0] = R + U + J;
  out[1] = R;
  out[2] = U + J;
}

// ---- tail: blocks 0..BB-1 = segment-mean + rating; block BB = U loss -------
// seg ids are repeat(arange(B), H=16): block b owns entries [16b,16b+16).
__global__ __launch_bounds__(256)
void k_tail(const int* __restrict__ u_idx, const int* __restrict__ i_idx,
            const float* __restrict__ rs, const float* __restrict__ label,
            const float* __restrict__ T_w, float* __restrict__ acc,
            float* __restrict__ out){
  __shared__ __align__(16) float smem[6500];
  const int b = blockIdx.x, t = threadIdx.x, w = t >> 6, j = t & 63;

  if (b == BB){
    // ================= U loss =================
    float* Tl  = smem;          // [32][202]
    float* nrm = smem + 6464;
    float* wred= smem + 6496;
    for (int i = t; i < DD * AA; i += 256){
      int d = i >> 5, a = i & 31;
      Tl[a * 202 + d] = T_w[i];
    }
    __syncthreads();
    if (t < AA){
      float s = 0.f;
      for (int d = 0; d < DD; d += 2){
        float2 v = *(float2*)&Tl[t * 202 + d];
        s += v.x * v.x + v.y * v.y;
      }
      nrm[t] = fmaxf(sqrtf(s), 1e-12f);
    }
    __syncthreads();
    int a = t >> 3, b0 = (t & 7) * 4;
    float d0 = 0, d1 = 0, d2 = 0, d3 = 0;
    for (int d = 0; d < DD; d += 2){
      float2 va = *(float2*)&Tl[a * 202 + d];
      float2 v0 = *(float2*)&Tl[(b0    ) * 202 + d];
      float2 v1 = *(float2*)&Tl[(b0 + 1) * 202 + d];
      float2 v2 = *(float2*)&Tl[(b0 + 2) * 202 + d];
      float2 v3 = *(float2*)&Tl[(b0 + 3) * 202 + d];
      d0 += va.x * v0.x + va.y * v0.y;
      d1 += va.x * v1.x + va.y * v1.y;
      d2 += va.x * v2.x + va.y * v2.y;
      d3 += va.x * v3.x + va.y * v3.y;
    }
    float na = nrm[a], gg = 0.f, g;
    g = d0 / (na * nrm[b0    ]) - (a == b0     ? 1.f : 0.f); gg += g * g;
    g = d1 / (na * nrm[b0 + 1]) - (a == b0 + 1 ? 1.f : 0.f); gg += g * g;
    g = d2 / (na * nrm[b0 + 2]) - (a == b0 + 2 ? 1.f : 0.f); gg += g * g;
    g = d3 / (na * nrm[b0 + 3]) - (a == b0 + 3 ? 1.f : 0.f); gg += g * g;
    float v = sum64(gg);
    if (j == 63) wred[w] = v;
    __syncthreads();
    if (t == 0){
      atomicAdd(&acc[1], (wred[0] + wred[1] + wred[2] + wred[3]) / (float)(AA * AA));
      __threadfence();
      int prev = atomicAdd((int*)acc + 8, 1);
      if (prev == BB) finalize(acc, out);
    }
    return;
  }

  // ================= segment-mean + rating =================
  int*   idxs = (int*)smem;        // 32
  float* wred = smem + 32;         // 4
  if (t < 16) idxs[t] = u_idx[b * 16 + t];
  else if (t < 32) idxs[t] = i_idx[b * 16 + (t - 16)];
  __syncthreads();
  float su = 0.f, si = 0.f;
  if (t < DD){
#pragma unroll
    for (int k = 0; k < 16; ++k) su += rs[(size_t)idxs[k] * DD + t];
#pragma unroll
    for (int k = 0; k < 16; ++k) si += rs[(size_t)idxs[16 + k] * DD + t];
  }
  float v = sum64(su * si);
  if (j == 63) wred[w] = v;
  __syncthreads();
  if (t == 0){
    float dot = wred[0] + wred[1] + wred[2] + wred[3];
    float pred = dot * (1.f / 256.f) + 3.5f;     // /16 /16
    float e = pred - label[b];
    atomicAdd(&acc[2], e * e);
    __threadfence();
    int prev = atomicAdd((int*)acc + 8, 1);
    if (prev == BB) finalize(acc, out);
  }
}

extern "C" void kernel_launch(void* const* d_in, const int* in_sizes, int n_in,
                              void* d_out, int out_size, void* d_ws, size_t ws_size,
                              hipStream_t stream){
  const int*   hist     = (const int*)  d_in[0];
  const float* rev_pos  = (const float*)d_in[1];
  const float* rev_neg  = (const float*)d_in[2];
  const float* label    = (const float*)d_in[5];
  const int*   u_idx    = (const int*)  d_in[6];
  const int*   i_idx    = (const int*)  d_in[8];
  const float* word_emb = (const float*)d_in[10];
  const float* M_w      = (const float*)d_in[11];
  const float* W_w      = (const float*)d_in[12];
  const float* W_b      = (const float*)d_in[13];
  const float* T_w      = (const float*)d_in[14];

  float* ws   = (float*)d_ws;
  float* rs   = ws + WS_RS;
  float* accp = ws + WS_ACC;

  hipMemsetAsync(accp, 0, 64, stream);   // zero J/U/RL accumulators + counter
  k_main<<<NN, 256, 0, stream>>>(hist, rev_pos, rev_neg, word_emb, M_w,
                                 W_w, W_b, T_w, rs, accp);
  k_tail<<<BB + 1, 256, 0, stream>>>(u_idx, i_idx, rs, label, T_w, accp,
                                     (float*)d_out);
}